// Round 11
// baseline (328.914 us; speedup 1.0000x reference)
//
#include <hip/hip_runtime.h>
#include <hip/hip_bf16.h>
#include <math.h>

typedef float f4 __attribute__((ext_vector_type(4)));

// Problem constants (seed-0 instance): N=2048, T=512, H=256, E=65536, K=10

// ---------------- Kernel 1: fused mean + proj + normalize ----------------
// (R10 winner, unchanged.) Phase 1: block-per-row NT streaming mean, 4-acc
// ILP, ~4.9 TB/s (= measured read-reduce ceiling). Phase 2: proj+normalize
// in-block from LDS.
__global__ __launch_bounds__(256) void mean_proj_kernel(const float* __restrict__ x,
                                                        const float* __restrict__ W,
                                                        float* __restrict__ e,
                                                        int T) {
    const int n   = blockIdx.x;
    const int tid = threadIdx.x;
    const int v   = tid & 63;   // float4 index within row (H/4 == 64)
    const int tg  = tid >> 6;   // wave id 0..3

    __shared__ f4    red[256];
    __shared__ float xs[256];
    __shared__ float pp[256];
    __shared__ float nrm[2];

    const f4* xr = reinterpret_cast<const f4*>(x + (size_t)n * T * 256);
    f4 a0 = {0.f, 0.f, 0.f, 0.f}, a1 = a0, a2 = a0, a3 = a0;
    for (int t = tg; t < T; t += 16) {
        a0 += __builtin_nontemporal_load(&xr[(t     ) * 64 + v]);
        a1 += __builtin_nontemporal_load(&xr[(t +  4) * 64 + v]);
        a2 += __builtin_nontemporal_load(&xr[(t +  8) * 64 + v]);
        a3 += __builtin_nontemporal_load(&xr[(t + 12) * 64 + v]);
    }
    red[tid] = (a0 + a1) + (a2 + a3);
    __syncthreads();
    if (tid < 64) {
        f4 o = (red[tid] + red[tid + 64]) + (red[tid + 128] + red[tid + 192]);
        o *= (1.0f / (float)T);
        *reinterpret_cast<f4*>(&xs[tid * 4]) = o;
    }
    __syncthreads();

    // proj partial: thread (j = tid&127, half = tid>>7) does c in [128h, 128h+128)
    {
        const int j    = tid & 127;
        const int half = tid >> 7;
        const float* Wr = W + (size_t)j * 256 + half * 128;
        const float* xh = xs + half * 128;
        float acc = 0.f;
        #pragma unroll 8
        for (int c = 0; c < 128; ++c) acc = fmaf(Wr[c], xh[c], acc);
        pp[tid] = acc;
    }
    __syncthreads();
    float accf = 0.f;
    if (tid < 128) {
        accf = pp[tid] + pp[tid + 128];
        float s = accf * accf;
        #pragma unroll
        for (int off = 32; off; off >>= 1) s += __shfl_xor(s, off);
        if ((tid & 63) == 0) nrm[tid >> 6] = s;
    }
    __syncthreads();
    if (tid < 128) {
        float inv = 1.0f / fmaxf(sqrtf(nrm[0] + nrm[1]), 1e-12f);
        e[(size_t)n * 128 + tid] = accf * inv;
    }
}

// ---------------- Kernel 2: sim + top-11 + dyn scatter (+fixed tail blocks) --
// Blocks [0, N/TK_ROWS): 4 sim rows each. Blocks >= N/TK_ROWS: fixed-edge
// copy/scale (merged to save a launch).
// Phase A (R11): 4-j blocking — thread carries 4 e-row streams; each eL f4
// broadcast (ds_read_b128) is reused across 4 j's -> LDS issue 1024->256
// b128/thread (phase A was LDS-issue-bound at ~41us: 1024*12cyc*8waves/CU).
// NO pragma unroll on c4 (R9 lesson); acc indices compile-time (rule #20).
// Phase B: wave w extracts top-11 (value desc, index asc), drops rank 0.
#define TK_ROWS 4
__global__ __launch_bounds__(256) void simtopk_kernel(const float* __restrict__ e,
                                                      const int* __restrict__ ei,
                                                      const float* __restrict__ ea,
                                                      const float* __restrict__ mix,
                                                      float* __restrict__ out,
                                                      int N /*2048*/, int E /*65536*/,
                                                      int nsimblk) {
    const int tid = threadIdx.x;
    const int M   = E + N * 10;  // 86016
    const float alpha = 1.0f / (1.0f + expf(-mix[0]));

    if ((int)blockIdx.x >= nsimblk) {
        // ---- fixed-edge tail blocks ----
        int idx = (blockIdx.x - nsimblk) * 256 + tid;
        if (idx < E) {
            out[idx]                 = (float)ei[idx];            // row0 fixed src
            out[(size_t)M + idx]     = (float)ei[E + idx];        // row1 fixed dst
            out[2 * (size_t)M + idx] = ea[idx] * (1.0f - alpha);  // fixed attr
        }
        return;
    }

    __shared__ __align__(16) float eL[TK_ROWS][128];
    __shared__ float simL[TK_ROWS][2048];

    const int i0 = blockIdx.x * TK_ROWS;

    {
        int r = tid >> 6;
        int c = tid & 63;
        const float* er = e + (size_t)(i0 + r) * 128;
        eL[r][c]      = er[c];
        eL[r][c + 64] = er[c + 64];
    }
    __syncthreads();

    if (N == 2048) {
        // Phase A: 2 passes, 4 j's per pass: j = p*1024 + tid + q*256
        for (int p = 0; p < 2; ++p) {
            const int j0 = p * 1024 + tid;
            const f4* ej = reinterpret_cast<const f4*>(e + (size_t)j0 * 128);
            float acc[TK_ROWS][4];
            #pragma unroll
            for (int r = 0; r < TK_ROWS; ++r)
                #pragma unroll
                for (int q = 0; q < 4; ++q) acc[r][q] = 0.f;

            for (int c4 = 0; c4 < 32; ++c4) {
                f4 v0 = ej[c4];
                f4 v1 = ej[c4 +  8192];   // +256 rows * 32 f4
                f4 v2 = ej[c4 + 16384];
                f4 v3 = ej[c4 + 24576];
                #pragma unroll
                for (int r = 0; r < TK_ROWS; ++r) {
                    f4 qv = *reinterpret_cast<const f4*>(&eL[r][c4 * 4]);
                    acc[r][0] = fmaf(v0.x, qv.x, acc[r][0]);
                    acc[r][0] = fmaf(v0.y, qv.y, acc[r][0]);
                    acc[r][0] = fmaf(v0.z, qv.z, acc[r][0]);
                    acc[r][0] = fmaf(v0.w, qv.w, acc[r][0]);
                    acc[r][1] = fmaf(v1.x, qv.x, acc[r][1]);
                    acc[r][1] = fmaf(v1.y, qv.y, acc[r][1]);
                    acc[r][1] = fmaf(v1.z, qv.z, acc[r][1]);
                    acc[r][1] = fmaf(v1.w, qv.w, acc[r][1]);
                    acc[r][2] = fmaf(v2.x, qv.x, acc[r][2]);
                    acc[r][2] = fmaf(v2.y, qv.y, acc[r][2]);
                    acc[r][2] = fmaf(v2.z, qv.z, acc[r][2]);
                    acc[r][2] = fmaf(v2.w, qv.w, acc[r][2]);
                    acc[r][3] = fmaf(v3.x, qv.x, acc[r][3]);
                    acc[r][3] = fmaf(v3.y, qv.y, acc[r][3]);
                    acc[r][3] = fmaf(v3.z, qv.z, acc[r][3]);
                    acc[r][3] = fmaf(v3.w, qv.w, acc[r][3]);
                }
            }
            #pragma unroll
            for (int r = 0; r < TK_ROWS; ++r)
                #pragma unroll
                for (int q = 0; q < 4; ++q)
                    simL[r][j0 + q * 256] = acc[r][q];
        }
    } else {
        for (int j = tid; j < N; j += 256) {
            const f4* ej = reinterpret_cast<const f4*>(e + (size_t)j * 128);
            float acc[TK_ROWS] = {0.f, 0.f, 0.f, 0.f};
            for (int c4 = 0; c4 < 32; ++c4) {
                f4 vv = ej[c4];
                #pragma unroll
                for (int r = 0; r < TK_ROWS; ++r) {
                    const float* el = &eL[r][c4 * 4];
                    acc[r] = fmaf(vv.x, el[0], acc[r]);
                    acc[r] = fmaf(vv.y, el[1], acc[r]);
                    acc[r] = fmaf(vv.z, el[2], acc[r]);
                    acc[r] = fmaf(vv.w, el[3], acc[r]);
                }
            }
            #pragma unroll
            for (int r = 0; r < TK_ROWS; ++r) simL[r][j] = acc[r];
        }
    }
    __syncthreads();

    // Phase B: wave w owns row i0+w
    const int w    = tid >> 6;
    const int lane = tid & 63;
    const int i    = i0 + w;

    float keepv = 0.f;
    int   keepi = 0;
    for (int round = 0; round < 11; ++round) {
        float bv = -3.0f;
        int   bi = N;  // larger than any real index so ties prefer real
        for (int t = 0; t < 32; ++t) {
            int j = t * 64 + lane;
            float v = simL[w][j];
            if (v > bv || (v == bv && j < bi)) { bv = v; bi = j; }
        }
        #pragma unroll
        for (int off = 32; off; off >>= 1) {
            float ov = __shfl_xor(bv, off);
            int   oi = __shfl_xor(bi, off);
            if (ov > bv || (ov == bv && oi < bi)) { bv = ov; bi = oi; }
        }
        if ((bi & 63) == lane && bi < N) simL[w][bi] = -3.0f;
        if (lane == round) { keepv = bv; keepi = bi; }
    }
    if (lane >= 1 && lane <= 10) {
        int kk  = lane - 1;
        int pos = i * 10 + kk;
        out[(size_t)E + pos]         = (float)i;      // row0: src
        out[(size_t)M + E + pos]     = (float)keepi;  // row1: dst
        out[2 * (size_t)M + E + pos] = keepv * alpha; // attr
    }
}

extern "C" void kernel_launch(void* const* d_in, const int* in_sizes, int n_in,
                              void* d_out, int out_size, void* d_ws, size_t ws_size,
                              hipStream_t stream) {
    const float* x   = (const float*)d_in[0];
    const int*   ei  = (const int*)d_in[1];
    const float* ea  = (const float*)d_in[2];
    const float* W   = (const float*)d_in[3];
    const float* mix = (const float*)d_in[4];

    const int H  = 256;
    const int E  = in_sizes[2];                       // 65536
    const int M  = out_size / 3;                      // 86016
    const int N  = (M - E) / 10;                      // 2048
    const int T  = (int)((size_t)in_sizes[0] / ((size_t)N * H)); // 512

    float* e   = (float*)d_ws;                        // N*128 floats (1 MB)
    float* out = (float*)d_out;

    const int nsimblk = N / TK_ROWS;                  // 512
    const int nfixblk = (E + 255) / 256;              // 256

    mean_proj_kernel<<<N, 256, 0, stream>>>(x, W, e, T);
    simtopk_kernel<<<nsimblk + nfixblk, 256, 0, stream>>>(e, ei, ea, mix, out, N, E, nsimblk);
}

// Round 12
// 277.050 us; speedup vs baseline: 1.1872x; 1.1872x over previous
//
#include <hip/hip_runtime.h>
#include <hip/hip_bf16.h>
#include <math.h>

typedef float f4 __attribute__((ext_vector_type(4)));

// Problem constants (seed-0 instance): N=2048, T=512, H=256, E=65536, K=10

// ---------------- Kernel 1: fused mean + proj + normalize ----------------
// (R10 winner, unchanged.) Phase 1: block-per-row NT streaming mean, 4-acc
// ILP, ~4.9 TB/s (= measured read-reduce ceiling). Phase 2: proj+normalize
// in-block from LDS.
__global__ __launch_bounds__(256) void mean_proj_kernel(const float* __restrict__ x,
                                                        const float* __restrict__ W,
                                                        float* __restrict__ e,
                                                        int T) {
    const int n   = blockIdx.x;
    const int tid = threadIdx.x;
    const int v   = tid & 63;   // float4 index within row (H/4 == 64)
    const int tg  = tid >> 6;   // wave id 0..3

    __shared__ f4    red[256];
    __shared__ float xs[256];
    __shared__ float pp[256];
    __shared__ float nrm[2];

    const f4* xr = reinterpret_cast<const f4*>(x + (size_t)n * T * 256);
    f4 a0 = {0.f, 0.f, 0.f, 0.f}, a1 = a0, a2 = a0, a3 = a0;
    for (int t = tg; t < T; t += 16) {
        a0 += __builtin_nontemporal_load(&xr[(t     ) * 64 + v]);
        a1 += __builtin_nontemporal_load(&xr[(t +  4) * 64 + v]);
        a2 += __builtin_nontemporal_load(&xr[(t +  8) * 64 + v]);
        a3 += __builtin_nontemporal_load(&xr[(t + 12) * 64 + v]);
    }
    red[tid] = (a0 + a1) + (a2 + a3);
    __syncthreads();
    if (tid < 64) {
        f4 o = (red[tid] + red[tid + 64]) + (red[tid + 128] + red[tid + 192]);
        o *= (1.0f / (float)T);
        *reinterpret_cast<f4*>(&xs[tid * 4]) = o;
    }
    __syncthreads();

    // proj partial: thread (j = tid&127, half = tid>>7) does c in [128h, 128h+128)
    {
        const int j    = tid & 127;
        const int half = tid >> 7;
        const float* Wr = W + (size_t)j * 256 + half * 128;
        const float* xh = xs + half * 128;
        float acc = 0.f;
        #pragma unroll 8
        for (int c = 0; c < 128; ++c) acc = fmaf(Wr[c], xh[c], acc);
        pp[tid] = acc;
    }
    __syncthreads();
    float accf = 0.f;
    if (tid < 128) {
        accf = pp[tid] + pp[tid + 128];
        float s = accf * accf;
        #pragma unroll
        for (int off = 32; off; off >>= 1) s += __shfl_xor(s, off);
        if ((tid & 63) == 0) nrm[tid >> 6] = s;
    }
    __syncthreads();
    if (tid < 128) {
        float inv = 1.0f / fmaxf(sqrtf(nrm[0] + nrm[1]), 1e-12f);
        e[(size_t)n * 128 + tid] = accf * inv;
    }
}

// ---------------- Kernel 2: sim rows + top-11 extraction + dyn scatter --------
// ROWS=4 rows per block, 256 threads.
// Phase A (R12): j-outer single-stream (the only L1-legal shape: 256 lines
// x 64B = 16KB < 32KB L1; q-stream blocking at q>=2 thrashed L1 in R3/R9/R11).
// qv reads come DIRECT FROM GLOBAL e (wave-uniform address -> scalar/L1
// path), not LDS: phase A was LDS-pipe-bound (4 ds_read_b128 per c4 x 12cy
// x 8 waves/CU ~ 41us device-wide). No eL staging at all.
// Phase B: wave w extracts top-11 (value desc, index asc), drops rank 0.
#define TK_ROWS 4
__global__ __launch_bounds__(256) void simtopk_kernel(const float* __restrict__ e,
                                                      const float* __restrict__ mix,
                                                      float* __restrict__ out,
                                                      int N /*2048*/, int E /*65536*/) {
    __shared__ float simL[TK_ROWS][2048];

    const int i0  = blockIdx.x * TK_ROWS;
    const int tid = threadIdx.x;
    const int M   = E + N * 10;  // 86016

    // uniform query-row pointers (2KB total, L1-resident after first pass)
    const f4* eq0 = reinterpret_cast<const f4*>(e + (size_t)(i0 + 0) * 128);
    const f4* eq1 = reinterpret_cast<const f4*>(e + (size_t)(i0 + 1) * 128);
    const f4* eq2 = reinterpret_cast<const f4*>(e + (size_t)(i0 + 2) * 128);
    const f4* eq3 = reinterpret_cast<const f4*>(e + (size_t)(i0 + 3) * 128);

    // Phase A: sims for all j, 4 rows at once (j outer, c4 inner)
    for (int j = tid; j < N; j += 256) {
        const f4* ej = reinterpret_cast<const f4*>(e + (size_t)j * 128);
        float acc0 = 0.f, acc1 = 0.f, acc2 = 0.f, acc3 = 0.f;
        #pragma unroll 4
        for (int c4 = 0; c4 < 32; ++c4) {
            f4 vv = ej[c4];
            f4 q0 = eq0[c4];
            f4 q1 = eq1[c4];
            f4 q2 = eq2[c4];
            f4 q3 = eq3[c4];
            acc0 = fmaf(vv.x, q0.x, acc0);
            acc0 = fmaf(vv.y, q0.y, acc0);
            acc0 = fmaf(vv.z, q0.z, acc0);
            acc0 = fmaf(vv.w, q0.w, acc0);
            acc1 = fmaf(vv.x, q1.x, acc1);
            acc1 = fmaf(vv.y, q1.y, acc1);
            acc1 = fmaf(vv.z, q1.z, acc1);
            acc1 = fmaf(vv.w, q1.w, acc1);
            acc2 = fmaf(vv.x, q2.x, acc2);
            acc2 = fmaf(vv.y, q2.y, acc2);
            acc2 = fmaf(vv.z, q2.z, acc2);
            acc2 = fmaf(vv.w, q2.w, acc2);
            acc3 = fmaf(vv.x, q3.x, acc3);
            acc3 = fmaf(vv.y, q3.y, acc3);
            acc3 = fmaf(vv.z, q3.z, acc3);
            acc3 = fmaf(vv.w, q3.w, acc3);
        }
        simL[0][j] = acc0;
        simL[1][j] = acc1;
        simL[2][j] = acc2;
        simL[3][j] = acc3;
    }
    __syncthreads();

    // Phase B: wave w owns row i0+w
    const int w    = tid >> 6;
    const int lane = tid & 63;
    const int i    = i0 + w;
    const float alpha = 1.0f / (1.0f + expf(-mix[0]));

    float keepv = 0.f;
    int   keepi = 0;
    for (int round = 0; round < 11; ++round) {
        float bv = -3.0f;
        int   bi = N;  // larger than any real index so ties prefer real
        for (int t = 0; t < 32; ++t) {
            int j = t * 64 + lane;
            float v = simL[w][j];
            if (v > bv || (v == bv && j < bi)) { bv = v; bi = j; }
        }
        #pragma unroll
        for (int off = 32; off; off >>= 1) {
            float ov = __shfl_xor(bv, off);
            int   oi = __shfl_xor(bi, off);
            if (ov > bv || (ov == bv && oi < bi)) { bv = ov; bi = oi; }
        }
        if ((bi & 63) == lane && bi < N) simL[w][bi] = -3.0f;
        if (lane == round) { keepv = bv; keepi = bi; }
    }
    if (lane >= 1 && lane <= 10) {
        int kk  = lane - 1;
        int pos = i * 10 + kk;
        out[(size_t)E + pos]         = (float)i;      // row0: src
        out[(size_t)M + E + pos]     = (float)keepi;  // row1: dst
        out[2 * (size_t)M + E + pos] = keepv * alpha; // attr
    }
}

// ---------------- Kernel 3: fixed edges copy/scale ----------------
__global__ __launch_bounds__(256) void fixed_kernel(const int* __restrict__ ei,
                                                    const float* __restrict__ ea,
                                                    const float* __restrict__ mix,
                                                    float* __restrict__ out,
                                                    int E, int M) {
    const int idx = blockIdx.x * blockDim.x + threadIdx.x;
    if (idx < E) {
        float alpha = 1.0f / (1.0f + expf(-mix[0]));
        out[idx]                 = (float)ei[idx];            // row0 fixed src
        out[(size_t)M + idx]     = (float)ei[E + idx];        // row1 fixed dst
        out[2 * (size_t)M + idx] = ea[idx] * (1.0f - alpha);  // fixed attr
    }
}

extern "C" void kernel_launch(void* const* d_in, const int* in_sizes, int n_in,
                              void* d_out, int out_size, void* d_ws, size_t ws_size,
                              hipStream_t stream) {
    const float* x   = (const float*)d_in[0];
    const int*   ei  = (const int*)d_in[1];
    const float* ea  = (const float*)d_in[2];
    const float* W   = (const float*)d_in[3];
    const float* mix = (const float*)d_in[4];

    const int H  = 256;
    const int E  = in_sizes[2];                       // 65536
    const int M  = out_size / 3;                      // 86016
    const int N  = (M - E) / 10;                      // 2048
    const int T  = (int)((size_t)in_sizes[0] / ((size_t)N * H)); // 512

    float* e   = (float*)d_ws;                        // N*128 floats (1 MB)
    float* out = (float*)d_out;

    mean_proj_kernel<<<N, 256, 0, stream>>>(x, W, e, T);
    simtopk_kernel<<<N / TK_ROWS, 256, 0, stream>>>(e, mix, out, N, E);
    fixed_kernel<<<(E + 255) / 256, 256, 0, stream>>>(ei, ea, mix, out, E, M);
}